// Round 6
// baseline (482.333 us; speedup 1.0000x reference)
//
#include <hip/hip_runtime.h>
#include <stdint.h>

// Problem constants
#define MROWS 32768      // B*S = 8*4096
#define KD    256        // 2*DIM
#define VOCABN 8192

typedef _Float16 half8  __attribute__((ext_vector_type(8)));
typedef _Float16 half4v __attribute__((ext_vector_type(4)));
typedef float  floatx4  __attribute__((ext_vector_type(4)));

// scratch layout (byte offsets within d_ws; ws_size >= WS_NEED verified R3/R4)
#define A_OFF     0u          // (unused since R20: af loaded from gr/gi direct)
#define B_OFF     16777216u   // f16 cb [8192][256]   =  4,194,304 B
#define CN_OFF    20971520u   // f32 0.5*||c||^2 [8192] = 32,768 B
#define PART_OFF  21004288u   // float4 top2 [32768][8] = 4,194,304 B
#define IDX_OFF   25198592u   // int idx [32768] = 131,072 B
#define WS_NEED   25329664u

// ---- top-2 (max sigma) with smaller-index tie-break (flush/merge path) ----
struct Top2 { float s1; int i1; float s2; int i2; };

__device__ __forceinline__ bool better(float sa, int ia, float sb, int ib) {
    return (sa > sb) || (sa == sb && ia < ib);
}
__device__ __forceinline__ Top2 merge2(const Top2& a, const Top2& b) {
    Top2 r;
    if (better(b.s1, b.i1, a.s1, a.i1)) {
        r.s1 = b.s1; r.i1 = b.i1;
        if (better(a.s1, a.i1, b.s2, b.i2)) { r.s2 = a.s1; r.i2 = a.i1; }
        else                                { r.s2 = b.s2; r.i2 = b.i2; }
    } else {
        r.s1 = a.s1; r.i1 = a.i1;
        if (better(b.s1, b.i1, a.s2, a.i2)) { r.s2 = b.s1; r.i2 = b.i1; }
        else                                { r.s2 = a.s2; r.i2 = a.i2; }
    }
    return r;
}

// async global->LDS, 16 B per lane. LDS dest is WAVE-UNIFORM base + lane*16;
// global src is per-lane (swizzle is applied by pre-permuting the src).
__device__ __forceinline__ void gll16(const void* g, const void* l) {
    __builtin_amdgcn_global_load_lds(
        (const __attribute__((address_space(1))) void*)g,
        (__attribute__((address_space(3))) void*)l, 16, 0, 0);
}

// counted-vmcnt pipe barrier (T3/T4): drain to N outstanding, raw s_barrier.
// NEVER vmcnt(0) in the main loop; sched_barrier(0) pins reordering.
#define PIPE_SYNC(N) do {                                        \
    asm volatile("s_waitcnt vmcnt(" #N ")" ::: "memory");        \
    __builtin_amdgcn_s_barrier();                                \
    __builtin_amdgcn_sched_barrier(0);                           \
} while (0)

// ---- 1. codebook f16 [8192][256] + 0.5*||c||^2 fp32 ----
__global__ __launch_bounds__(64) void prep_c(const float* __restrict__ cb,
                                             _Float16* __restrict__ B,
                                             float* __restrict__ cnorm) {
    int v = blockIdx.x;
    int lane = threadIdx.x;                    // 0..63, 4 floats each
    float4 c = ((const float4*)(cb + (size_t)v * 256))[lane];
    half4v h;
    h[0] = (_Float16)c.x; h[1] = (_Float16)c.y;
    h[2] = (_Float16)c.z; h[3] = (_Float16)c.w;
    ((half4v*)(B + (size_t)v * 256))[lane] = h;
    float s = c.x * c.x + c.y * c.y + c.z * c.z + c.w * c.w;
    #pragma unroll
    for (int m = 32; m; m >>= 1) s += __shfl_xor(s, m);
    if (lane == 0) cnorm[v] = 0.5f * s;
}

// ---- 2. f16 GEMM + per-row top-2 argmax(sigma) ----
// R20 post-mortem: grid 1024 + 52 KB LDS still gave 2 blocks/CU (22%) --
// 3x52=156<=160 "fits", so the EFFECTIVE co-residency LDS pool is smaller
// than nominal (~128 KB or granule rounding). R21: restructure to 34 KB:
// 4x1 wave decomposition (wave = 16 rows x all 128 cols) -> every output
// row owned by ONE wave: FLUSH = butterfly + direct part store, NO topbuf,
// NO cross-wave merge, NO flush barriers; t2 32->16 regs, af 64->32 regs.
// Sub-slice = 64 cols x 64 k = 8 KB with 128-B rows (proven conflict-free
// geometry; R17's conflicts were 64-B rows, not small buffers). 4 buffers
// x 8 KB + 2 KB cnorm = 34 KB -> 3 blocks/CU even under a 128-KB pool,
// 4 under 160. 8 steps/g, stage-ahead 3 ((u+3)&3 != u&3, compile-time),
// PIPE_SYNC(4)/step = same counted depth as R19. Cost: each wave reads all
// cols -> 2x ds_read volume (LDS floor 27->53 us, still < 66-us MFMA floor).
// vmcnt ledger: steady state outstanding {st(u+1),st(u+2)}=4; stage(u+3)
// ->6; sync(4) completes st(u+1). FLUSH stores and wave0's cnorm ride-along
// only cause earlier drains, never missed ones.
__global__ __launch_bounds__(256) void gemm_argmin(const float* __restrict__ gr,
                                                   const float* __restrict__ gi,
                                                   const _Float16* __restrict__ B,
                                                   const float* __restrict__ cnorm,
                                                   float4* __restrict__ part) {
    // LDS: 4 x 8 KB sub-slice buffers | 2 x 1 KB cnorm = 34 KB
    __shared__ __align__(16) char lds[34816];

    const int tid = threadIdx.x;
    const int bid = blockIdx.x;
    const int nh  = bid & 1;                  // vocab half (4096 cols = 32 g)
    const int m0  = (bid >> 1) * 64;
    const int wave = tid >> 6, lane = tid & 63;
    const int lane16 = lane & 15, quad = lane >> 4;

    // A-fragments: wave owns rows m0+wave*16+lane16 (16 rows); k = hs*64 +
    // ks*32 + quad*8. Loaded f32 from gr/gi + converted (same rounding as
    // the old prep_z). Register-resident: af[4][2] = 32 VGPR.
    half8 af[4][2];
    {
        const int row = m0 + wave * 16 + lane16;
        const float* zr = gr + (size_t)row * 128 + quad * 8;
        const float* zi = gi + (size_t)row * 128 + quad * 8;
        #pragma unroll
        for (int hs = 0; hs < 4; ++hs)
            #pragma unroll
            for (int ks = 0; ks < 2; ++ks) {
                const int kb = hs * 64 + ks * 32;        // 0..224, static
                const float* p = (kb < 128) ? (zr + kb) : (zi + (kb - 128));
                float4 lo = *(const float4*)p;
                float4 hi = *(const float4*)(p + 4);
                half8 hf;
                hf[0] = (_Float16)lo.x; hf[1] = (_Float16)lo.y;
                hf[2] = (_Float16)lo.z; hf[3] = (_Float16)lo.w;
                hf[4] = (_Float16)hi.x; hf[5] = (_Float16)hi.y;
                hf[6] = (_Float16)hi.z; hf[7] = (_Float16)hi.w;
                af[hs][ks] = hf;
            }
    }

    // ---- staging geometry (8-KB sub-slice = [64 cols][128 B of k]) ----
    // v = global sub-slice 0..255: gg=v>>3, hs=(v>>1)&3, c=v&1. Wave stages
    // cols [wave*16, wave*16+16) of the sub-slice as 2 gll16 of 1 KB (8 cols
    // each). Lane L -> col8 = L>>3, phys chunk L&7, fetch LOGICAL chunk
    // (L&7)^(L>>3) (col&7 == L>>3), so the XOR'd reader sees B[col][k].
    const int l3 = lane >> 3, l7 = lane & 7;
    const _Float16* pbase = B + ((size_t)nh * 4096 + wave * 16 + l3) * 256
                          + (l7 ^ l3) * 8;
    auto STAGE = [&](int v) {
        const _Float16* src = pbase
            + ((size_t)(v >> 3) * 128 + (size_t)((v & 1) * 64)) * 256
            + ((v >> 1) & 3) * 64;
        char* dst = lds + (v & 3) * 8192 + wave * 2048;
        gll16(src,            dst);
        gll16(src + 8 * 256,  dst + 1024);
    };

    // fragment ds_read offsets (bytes within an 8-KB buffer):
    // off(j4,ks) = (j4*16+lane16)*128 + ((ks*4+quad) ^ (lane16&7))*16
    const uint32_t fr_base = (uint32_t)lane16 * 128;
    uint32_t cq[2];
    #pragma unroll
    for (int ks = 0; ks < 2; ++ks)
        cq[ks] = (uint32_t)(((ks * 4 + quad) ^ (lane16 & 7)) * 16);

    // compute step hh (buffer hh&3, k-chunk hs=hh>>1, col-half c=hh&1):
    // 8 ds_read_b128 + 8 MFMA into acc[c*4+j4] (static indices under unroll)
    auto COMPUTE = [&](int hh, floatx4 (&acc)[8]) {
        const char* cur = lds + (hh & 3) * 8192;
        half8 bf[4][2];
        #pragma unroll
        for (int j4 = 0; j4 < 4; ++j4)
            #pragma unroll
            for (int ks = 0; ks < 2; ++ks)
                bf[j4][ks] = *(const half8*)(cur + fr_base + j4 * 2048 + cq[ks]);
        #pragma unroll
        for (int ks = 0; ks < 2; ++ks)
            #pragma unroll
            for (int j4 = 0; j4 < 4; ++j4)
                acc[(hh & 1) * 4 + j4] = __builtin_amdgcn_mfma_f32_16x16x32_f16(
                    af[hh >> 1][ks], bf[j4][ks], acc[(hh & 1) * 4 + j4], 0, 0, 0);
    };

    auto ACCINIT = [&](int g, floatx4 (&acc)[8]) {     // g local
        const float* cl = (const float*)(lds + 32768 + (g & 1) * 1024);
        #pragma unroll
        for (int j = 0; j < 8; ++j) {
            float v = -cl[j * 16 + lane16];
            acc[j] = (floatx4){v, v, v, v};
        }
    };

    Top2 t2[4];
    #pragma unroll
    for (int r = 0; r < 4; ++r)
        t2[r] = Top2{-3.4e38f, 0x7fffffff, -3.4e38f, 0x7fffffff};

    // streaming top-2 (C/D layout: col=lane&15, row=quad*4+r). Cheap form;
    // exact ties deferred to resolve's fp64 refine. gG = GLOBAL g.
    auto TOP2 = [&](int gG, floatx4 (&acc)[8]) {
        const int colb = gG * 128 + lane16;
        #pragma unroll
        for (int r = 0; r < 4; ++r) {
            Top2& t = t2[r];
            #pragma unroll
            for (int j = 0; j < 8; ++j) {
                float sv = acc[j][r];
                int col = colb + j * 16;
                bool gt1 = sv > t.s1;
                bool gt2 = sv > t.s2;
#if __has_builtin(__builtin_amdgcn_fmed3f)
                float ns2 = __builtin_amdgcn_fmed3f(sv, t.s2, t.s1);
#else
                float ns2 = gt1 ? t.s1 : (gt2 ? sv : t.s2);
#endif
                t.i2 = gt1 ? t.i1 : (gt2 ? col : t.i2);
                t.i1 = gt1 ? col : t.i1;
                t.s1 = gt1 ? sv  : t.s1;
                t.s2 = ns2;
            }
        }
    };

    // flush: 16-lane butterfly, then lane16==0 stores its row's top-2
    // DIRECTLY to part (wave owns the row) -- no topbuf, no barriers.
    // The 4 global stores enter vmcnt; they only make later PIPE_SYNCs
    // drain staged loads EARLIER (never later) -> invariant safe.
    auto FLUSH = [&](int slot) {
        #pragma unroll
        for (int r = 0; r < 4; ++r) {
            Top2 t = t2[r];
            #pragma unroll
            for (int m = 1; m < 16; m <<= 1) {
                Top2 o;
                o.s1 = __shfl_xor(t.s1, m); o.i1 = __shfl_xor(t.i1, m);
                o.s2 = __shfl_xor(t.s2, m); o.i2 = __shfl_xor(t.i2, m);
                t = merge2(t, o);
            }
            if (lane16 == 0) {
                int row = m0 + wave * 16 + quad * 4 + r;
                part[(size_t)row * 8 + slot] =
                    make_float4(t.s1, __int_as_float(t.i1),
                                t.s2, __int_as_float(t.i2));
            }
            t2[r] = Top2{-3.4e38f, 0x7fffffff, -3.4e38f, 0x7fffffff};
        }
    };

    // prologue: cnorm(g0) + sub-slices 0..2; sync(4) drains af + cn + st0
    if (wave == 0)
        gll16(cnorm + (size_t)(nh * 32) * 128 + (lane & 31) * 4, lds + 32768);
    STAGE(0); STAGE(1); STAGE(2);
    PIPE_SYNC(4);

    for (int g = 0; g < 31; ++g) {
        floatx4 acc[8];
        ACCINIT(g, acc);
        const int u0 = g * 8;
        #pragma unroll
        for (int hh = 0; hh < 8; ++hh) {
            STAGE(u0 + hh + 3);
            if (hh == 3 && wave == 0)   // cnorm for g+1 rides the pipe
                gll16(cnorm + (size_t)(nh * 32 + g + 1) * 128 + (lane & 31) * 4,
                      lds + 32768 + ((g + 1) & 1) * 1024);
            COMPUTE(hh, acc);
            PIPE_SYNC(4);
        }
        TOP2(nh * 32 + g, acc);
        if ((g & 7) == 7) FLUSH((g >> 3) + nh * 4);
    }
    {   // g = 31 peeled: stages 251..255 then descending drains 4/4/4/4/4,2,0
        floatx4 acc[8];
        ACCINIT(31, acc);
        #pragma unroll
        for (int hh = 0; hh < 5; ++hh) {
            STAGE(251 + hh);
            COMPUTE(hh, acc);
            PIPE_SYNC(4);
        }
        COMPUTE(5, acc); PIPE_SYNC(2);
        COMPUTE(6, acc); PIPE_SYNC(0);
        COMPUTE(7, acc);
        TOP2(nh * 32 + 31, acc);
        FLUSH(3 + nh * 4);
    }
}

// ---- 3. resolve: merge 8 partials/row + WAVE-COOPERATIVE fp64 refine ----
// Compact (row,cand) pairs to LDS, one wave per candidate (64 lanes x 4 dims,
// fp64 shuffle-reduce), then each row scans its results. zero_vq folded in.
__global__ __launch_bounds__(256) void resolve(const float4* __restrict__ part,
                                               const float* __restrict__ gr,
                                               const float* __restrict__ gi,
                                               const float* __restrict__ cb,
                                               int* __restrict__ idx,
                                               float* __restrict__ out,
                                               size_t vq_off) {
    __shared__ int s_cnt;
    __shared__ int2 ent[2048];
    __shared__ double res[2048];

    const int tid = threadIdx.x;
    const int row = blockIdx.x * 256 + tid;   // grid 128
    if (blockIdx.x == 0 && tid == 0) out[vq_off] = 0.f;
    if (tid == 0) s_cnt = 0;

    float4 e[8];
    #pragma unroll
    for (int j = 0; j < 8; ++j) e[j] = part[(size_t)row * 8 + j];
    Top2 t{-3.4e38f, 0x7fffffff, -3.4e38f, 0x7fffffff};
    #pragma unroll
    for (int j = 0; j < 8; ++j) {
        Top2 o{e[j].x, __float_as_int(e[j].y), e[j].z, __float_as_int(e[j].w)};
        t = merge2(t, o);
    }
    int best = t.i1;
    const float MARGIN = 0.12f;   // ~7.7 sigma of f16-screen score-diff noise
    const float cut = t.s1 - MARGIN;
    const bool need = (t.s1 - t.s2 < MARGIN);
    __syncthreads();              // s_cnt initialized

    int nc = 0;
    if (need) {
        #pragma unroll
        for (int j = 0; j < 8; ++j)
            #pragma unroll
            for (int c = 0; c < 2; ++c) {
                float sv = c ? e[j].z : e[j].x;
                int   ci = __float_as_int(c ? e[j].w : e[j].y);
                nc += (sv >= cut && (unsigned)ci < 8192u) ? 1 : 0;
            }
    }
    int mybase = 0;
    bool serial = false;
    if (nc) {
        mybase = atomicAdd(&s_cnt, nc);
        if (mybase + nc <= 2048) {
            int k = 0;
            #pragma unroll
            for (int j = 0; j < 8; ++j)
                #pragma unroll
                for (int c = 0; c < 2; ++c) {
                    float sv = c ? e[j].z : e[j].x;
                    int   ci = __float_as_int(c ? e[j].w : e[j].y);
                    if (sv >= cut && (unsigned)ci < 8192u)
                        ent[mybase + (k++)] = make_int2(row, ci);
                }
        } else serial = true;     // overflow fallback (needs >8 cands/row avg)
    }
    __syncthreads();
    const int cnt = (s_cnt < 2048) ? s_cnt : 2048;
    const int wave = tid >> 6, lane = tid & 63;
    for (int ee = wave; ee < cnt; ee += 4) {
        int2 rc = ent[ee];
        float4 c4 = ((const float4*)(cb + (size_t)rc.y * 256))[lane];
        float4 z4 = (lane < 32)
                  ? ((const float4*)(gr + (size_t)rc.x * 128))[lane]
                  : ((const float4*)(gi + (size_t)rc.x * 128))[lane - 32];
        double dx = (double)z4.x - (double)c4.x;
        double dy = (double)z4.y - (double)c4.y;
        double dz = (double)z4.z - (double)c4.z;
        double dw = (double)z4.w - (double)c4.w;
        double d = dx * dx + dy * dy + dz * dz + dw * dw;
        #pragma unroll
        for (int m = 1; m < 64; m <<= 1) d += __shfl_xor(d, m);
        if (lane == 0) res[ee] = d;
    }
    __syncthreads();
    if (nc && !serial) {
        double bd = 1e300; int bi = 0x7fffffff;
        for (int k = 0; k < nc; ++k) {
            double d = res[mybase + k];
            int   ci = ent[mybase + k].y;
            if (d < bd || (d == bd && ci < bi)) { bd = d; bi = ci; }
        }
        if ((unsigned)bi < 8192u) best = bi;
    } else if (serial) {          // old proven serial path (rare)
        double bd = 1e300; int bi = 0x7fffffff;
        const float* zr = gr + (size_t)row * 128;
        const float* zi = gi + (size_t)row * 128;
        #pragma unroll
        for (int j = 0; j < 8; ++j)
            #pragma unroll
            for (int c = 0; c < 2; ++c) {
                float sv = c ? e[j].z : e[j].x;
                int   ci = __float_as_int(c ? e[j].w : e[j].y);
                if (sv >= cut && (unsigned)ci < 8192u) {
                    const float* crow = cb + (size_t)ci * 256;
                    double d = 0.0;
                    for (int k = 0; k < 128; ++k) {
                        double a = (double)zr[k] - (double)crow[k];
                        double b = (double)zi[k] - (double)crow[128 + k];
                        d += a * a + b * b;
                    }
                    if (d < bd || (d == bd && ci < bi)) { bd = d; bi = ci; }
                }
            }
        if ((unsigned)bi < 8192u) best = bi;
    }
    idx[row] = ((unsigned)best < 8192u) ? best : 0;
}

// ---- 4. gather + proposal(REAL part only) + salience + vq (one wave/row) ----
__global__ __launch_bounds__(256) void gather_epi(const int* __restrict__ idx,
                                                  const float* __restrict__ gr,
                                                  const float* __restrict__ gi,
                                                  const float* __restrict__ cb,
                                                  const float* __restrict__ salw,
                                                  const float* __restrict__ salb,
                                                  float* __restrict__ out,
                                                  size_t sal_off, size_t vq_off) {
    const int wave = threadIdx.x >> 6, lane = threadIdx.x & 63;
    const int row = blockIdx.x * 4 + wave;
    int id = idx[row];
    if ((unsigned)id >= 8192u) id = 0;   // clamp: no wild reads

    float4 c4 = ((const float4*)(cb + (size_t)id * 256))[lane];
    float4 z4 = (lane < 32) ? ((const float4*)(gr + (size_t)row * 128))[lane]
                            : ((const float4*)(gi + (size_t)row * 128))[lane - 32];

    float dx = c4.x - z4.x, dy = c4.y - z4.y, dz = c4.z - z4.z, dw = c4.w - z4.w;
    float vq = dx * dx + dy * dy + dz * dz + dw * dw;
    float4 w4 = ((const float4*)salw)[lane];
    float sal = c4.x * w4.x + c4.y * w4.y + c4.z * w4.z + c4.w * w4.w;
    #pragma unroll
    for (int m = 1; m < 64; m <<= 1) {
        vq  += __shfl_xor(vq, m);
        sal += __shfl_xor(sal, m);
    }

    // proposal: real part only — lanes 0..31 hold c[0..128) as float4s
    if (lane < 32 && (size_t)(row + 1) * 128 <= sal_off) {
        float4* op = (float4*)(out + (size_t)row * 128);
        op[lane] = c4;
    }
    if (lane == 0 && sal_off + row < vq_off)
        out[sal_off + row] = sal + salb[0];

    __shared__ float vqs[4];
    if (lane == 0) vqs[wave] = vq;
    __syncthreads();
    if (threadIdx.x == 0) {
        float p = (vqs[0] + vqs[1] + vqs[2] + vqs[3]) * (1.25f / 8388608.f);
        atomicAdd(out + vq_off, p);
    }
}

extern "C" void kernel_launch(void* const* d_in, const int* in_sizes, int n_in,
                              void* d_out, int out_size, void* d_ws, size_t ws_size,
                              hipStream_t stream) {
    const float* gr = (const float*)d_in[0];   // gw_real  [8,4096,128]
    const float* gi = (const float*)d_in[1];   // gw_imag  [8,4096,128]
    const float* cb = (const float*)d_in[2];   // codebook [8192,256]
    const float* sw = (const float*)d_in[3];   // sal_w    [1,256]
    const float* sb = (const float*)d_in[4];   // sal_b    [1]
    float* out = (float*)d_out;

    // Output offsets (out_size = 4,227,073 floats:
    // proposal-real 4,194,304 | salience 32,768 | vq_loss 1).
    size_t vq_off  = (size_t)out_size - 1;
    size_t sal_off = (size_t)out_size - 1 - 32768;

    char* base = (char*)d_ws;
    int*  idxb = (int*)(base + IDX_OFF);
    _Float16* Bq   = (_Float16*)(base + B_OFF);
    float*    cn   = (float*)   (base + CN_OFF);
    float4*   part = (float4*)  (base + PART_OFF);

    prep_c<<<8192, 64, 0, stream>>>(cb, Bq, cn);
    gemm_argmin<<<1024, 256, 0, stream>>>(gr, gi, Bq, cn, part);
    resolve<<<128, 256, 0, stream>>>(part, gr, gi, cb, idxb, out, vq_off);
    gather_epi<<<8192, 256, 0, stream>>>(idxb, gr, gi, cb, sw, sb, out,
                                         sal_off, vq_off);
}

// Round 7
// 470.834 us; speedup vs baseline: 1.0244x; 1.0244x over previous
//
#include <hip/hip_runtime.h>
#include <stdint.h>

// Problem constants
#define MROWS 32768      // B*S = 8*4096
#define KD    256        // 2*DIM
#define VOCABN 8192

typedef _Float16 half8  __attribute__((ext_vector_type(8)));
typedef _Float16 half4v __attribute__((ext_vector_type(4)));
typedef float  floatx4  __attribute__((ext_vector_type(4)));

// scratch layout (byte offsets within d_ws; ws_size >= WS_NEED verified R3/R4)
#define A_OFF     0u          // (unused since R20: af loaded from gr/gi direct)
#define B_OFF     16777216u   // f16 cb [8192][256]   =  4,194,304 B
#define CN_OFF    20971520u   // f32 0.5*||c||^2 [8192] = 32,768 B
#define PART_OFF  21004288u   // float4 top2 [32768][8] = 4,194,304 B
#define IDX_OFF   25198592u   // int idx [32768] = 131,072 B
#define WS_NEED   25329664u

// ---- top-2 (max sigma) with smaller-index tie-break (flush/merge path) ----
struct Top2 { float s1; int i1; float s2; int i2; };

__device__ __forceinline__ bool better(float sa, int ia, float sb, int ib) {
    return (sa > sb) || (sa == sb && ia < ib);
}
__device__ __forceinline__ Top2 merge2(const Top2& a, const Top2& b) {
    Top2 r;
    if (better(b.s1, b.i1, a.s1, a.i1)) {
        r.s1 = b.s1; r.i1 = b.i1;
        if (better(a.s1, a.i1, b.s2, b.i2)) { r.s2 = a.s1; r.i2 = a.i1; }
        else                                { r.s2 = b.s2; r.i2 = b.i2; }
    } else {
        r.s1 = a.s1; r.i1 = a.i1;
        if (better(b.s1, b.i1, a.s2, a.i2)) { r.s2 = b.s1; r.i2 = b.i1; }
        else                                { r.s2 = a.s2; r.i2 = a.i2; }
    }
    return r;
}

// async global->LDS, 16 B per lane. LDS dest is WAVE-UNIFORM base + lane*16;
// global src is per-lane (swizzle is applied by pre-permuting the src).
__device__ __forceinline__ void gll16(const void* g, const void* l) {
    __builtin_amdgcn_global_load_lds(
        (const __attribute__((address_space(1))) void*)g,
        (__attribute__((address_space(3))) void*)l, 16, 0, 0);
}

// counted-vmcnt pipe barrier (T3/T4): drain to N outstanding, raw s_barrier.
// NEVER vmcnt(0) in the main loop; sched_barrier(0) pins reordering.
#define PIPE_SYNC(N) do {                                        \
    asm volatile("s_waitcnt vmcnt(" #N ")" ::: "memory");        \
    __builtin_amdgcn_s_barrier();                                \
    __builtin_amdgcn_sched_barrier(0);                           \
} while (0)

// ---- 1. codebook f16 [8192][256] + 0.5*||c||^2 fp32 (4 rows/block) ----
__global__ __launch_bounds__(256) void prep_c(const float* __restrict__ cb,
                                              _Float16* __restrict__ B,
                                              float* __restrict__ cnorm) {
    int v = blockIdx.x * 4 + (threadIdx.x >> 6);
    int lane = threadIdx.x & 63;               // 0..63, 4 floats each
    float4 c = ((const float4*)(cb + (size_t)v * 256))[lane];
    half4v h;
    h[0] = (_Float16)c.x; h[1] = (_Float16)c.y;
    h[2] = (_Float16)c.z; h[3] = (_Float16)c.w;
    ((half4v*)(B + (size_t)v * 256))[lane] = h;
    float s = c.x * c.x + c.y * c.y + c.z * c.z + c.w * c.w;
    #pragma unroll
    for (int m = 32; m; m >>= 1) s += __shfl_xor(s, m);
    if (lane == 0) cnorm[v] = 0.5f * s;
}

// ---- 2. f16 GEMM + per-row top-2 argmax(sigma) ----
// R21 post-mortem: 34 KB LDS, 88 VGPR, grid 1024 -- STILL 2 blocks/CU
// (22.7%) across 68/52/34 KB: the blocks/CU pin is not LDS/VGPR/grid.
// And R19<->R21 show period scales with per-step work at fixed occupancy:
// the kernel is per-wave ISSUE/SERIAL-bound (blocking MFMA + ds lat + VALU
// in one serial chain, 2 waves/SIMD can't fill it). R22: stop adding
// blocks, add WAVES: 512-thread blocks (8 waves), M=128/block (wave owns
// 16 rows -- per-wave datapath byte-identical to R21: 8-KB sub-slices,
// same swizzle, 8 ds_read + 8 MFMA + TOP2/step). grid = 256 Mtiles x 2
// vocab halves = 512 = 2 blocks/CU = 16 waves/CU = 4 waves/SIMD, ONE
// dispatch round. Staging: 1 gll16/wave/step -> PIPE_SYNC(2) (ledger:
// sync completes st(u+1) each step; cn issued before STAGE(0) in
// prologue / after STAGE at hh==3 in-loop, always complete before its
// ACCINIT). launch_bounds(512,2) caps VGPR >= 128 >> 88 demand.
// Floors: MFMA 66 us; LDS-read pipe 16 waves x 8 b128 x 12cy = 1536
// cy/step -> ~164 us; L2 staging 62 us.
__global__ __launch_bounds__(512, 2) void gemm_argmin(const float* __restrict__ gr,
                                                      const float* __restrict__ gi,
                                                      const _Float16* __restrict__ B,
                                                      const float* __restrict__ cnorm,
                                                      float4* __restrict__ part) {
    // LDS: 4 x 8 KB sub-slice buffers | 2 x 1 KB cnorm = 34 KB
    __shared__ __align__(16) char lds[34816];

    const int tid = threadIdx.x;
    const int bid = blockIdx.x;
    const int nh  = bid & 1;                  // vocab half (4096 cols = 32 g)
    const int m0  = (bid >> 1) * 128;
    const int wave = tid >> 6, lane = tid & 63;
    const int lane16 = lane & 15, quad = lane >> 4;

    // A-fragments: wave owns rows m0+wave*16+lane16 (16 rows); k = hs*64 +
    // ks*32 + quad*8. Loaded f32 from gr/gi + converted (same rounding as
    // prep_z did). Register-resident: af[4][2] = 32 VGPR.
    half8 af[4][2];
    {
        const int row = m0 + wave * 16 + lane16;
        const float* zr = gr + (size_t)row * 128 + quad * 8;
        const float* zi = gi + (size_t)row * 128 + quad * 8;
        #pragma unroll
        for (int hs = 0; hs < 4; ++hs)
            #pragma unroll
            for (int ks = 0; ks < 2; ++ks) {
                const int kb = hs * 64 + ks * 32;        // 0..224, static
                const float* p = (kb < 128) ? (zr + kb) : (zi + (kb - 128));
                float4 lo = *(const float4*)p;
                float4 hi = *(const float4*)(p + 4);
                half8 hf;
                hf[0] = (_Float16)lo.x; hf[1] = (_Float16)lo.y;
                hf[2] = (_Float16)lo.z; hf[3] = (_Float16)lo.w;
                hf[4] = (_Float16)hi.x; hf[5] = (_Float16)hi.y;
                hf[6] = (_Float16)hi.z; hf[7] = (_Float16)hi.w;
                af[hs][ks] = hf;
            }
    }

    // ---- staging geometry (8-KB sub-slice = [64 cols][128 B of k]) ----
    // v = sub-slice 0..255: gg=v>>3, hs=(v>>1)&3, c=v&1. Each wave stages
    // cols [wave*8, wave*8+8) of the sub-slice = 1 KB = ONE gll16.
    // Lane L -> col8 = L>>3, phys chunk L&7, fetch LOGICAL chunk
    // (L&7)^(L>>3) (col&7 == L>>3 since wave*8 is 8-aligned), so the
    // XOR'd reader sees B[col][k]. (R21-proven: zero bank conflicts.)
    const int l3 = lane >> 3, l7 = lane & 7;
    const _Float16* pbase = B + ((size_t)nh * 4096 + wave * 8 + l3) * 256
                          + (l7 ^ l3) * 8;
    auto STAGE = [&](int v) {
        const _Float16* src = pbase
            + ((size_t)(v >> 3) * 128 + (size_t)((v & 1) * 64)) * 256
            + ((v >> 1) & 3) * 64;
        gll16(src, lds + (v & 3) * 8192 + wave * 1024);
    };

    // fragment ds_read offsets (bytes within an 8-KB buffer):
    // off(j4,ks) = (j4*16+lane16)*128 + ((ks*4+quad) ^ (lane16&7))*16
    const uint32_t fr_base = (uint32_t)lane16 * 128;
    uint32_t cq[2];
    #pragma unroll
    for (int ks = 0; ks < 2; ++ks)
        cq[ks] = (uint32_t)(((ks * 4 + quad) ^ (lane16 & 7)) * 16);

    // compute step hh (buffer hh&3, k-chunk hs=hh>>1, col-half c=hh&1):
    // 8 ds_read_b128 + 8 MFMA into acc[c*4+j4] (static under unroll)
    auto COMPUTE = [&](int hh, floatx4 (&acc)[8]) {
        const char* cur = lds + (hh & 3) * 8192;
        half8 bf[4][2];
        #pragma unroll
        for (int j4 = 0; j4 < 4; ++j4)
            #pragma unroll
            for (int ks = 0; ks < 2; ++ks)
                bf[j4][ks] = *(const half8*)(cur + fr_base + j4 * 2048 + cq[ks]);
        #pragma unroll
        for (int ks = 0; ks < 2; ++ks)
            #pragma unroll
            for (int j4 = 0; j4 < 4; ++j4)
                acc[(hh & 1) * 4 + j4] = __builtin_amdgcn_mfma_f32_16x16x32_f16(
                    af[hh >> 1][ks], bf[j4][ks], acc[(hh & 1) * 4 + j4], 0, 0, 0);
    };

    auto ACCINIT = [&](int g, floatx4 (&acc)[8]) {     // g local
        const float* cl = (const float*)(lds + 32768 + (g & 1) * 1024);
        #pragma unroll
        for (int j = 0; j < 8; ++j) {
            float v = -cl[j * 16 + lane16];
            acc[j] = (floatx4){v, v, v, v};
        }
    };

    Top2 t2[4];
    #pragma unroll
    for (int r = 0; r < 4; ++r)
        t2[r] = Top2{-3.4e38f, 0x7fffffff, -3.4e38f, 0x7fffffff};

    // streaming top-2 (C/D layout: col=lane&15, row=quad*4+r). Cheap form;
    // exact ties deferred to resolve's fp64 refine. gG = GLOBAL g.
    auto TOP2 = [&](int gG, floatx4 (&acc)[8]) {
        const int colb = gG * 128 + lane16;
        #pragma unroll
        for (int r = 0; r < 4; ++r) {
            Top2& t = t2[r];
            #pragma unroll
            for (int j = 0; j < 8; ++j) {
                float sv = acc[j][r];
                int col = colb + j * 16;
                bool gt1 = sv > t.s1;
                bool gt2 = sv > t.s2;
#if __has_builtin(__builtin_amdgcn_fmed3f)
                float ns2 = __builtin_amdgcn_fmed3f(sv, t.s2, t.s1);
#else
                float ns2 = gt1 ? t.s1 : (gt2 ? sv : t.s2);
#endif
                t.i2 = gt1 ? t.i1 : (gt2 ? col : t.i2);
                t.i1 = gt1 ? col : t.i1;
                t.s1 = gt1 ? sv  : t.s1;
                t.s2 = ns2;
            }
        }
    };

    // flush: 16-lane butterfly, then lane16==0 stores its row's top-2
    // DIRECTLY to part (wave owns the row) -- no topbuf, no barriers.
    // The global stores enter vmcnt; they only make later PIPE_SYNCs
    // drain staged loads EARLIER (never later) -> invariant safe.
    auto FLUSH = [&](int slot) {
        #pragma unroll
        for (int r = 0; r < 4; ++r) {
            Top2 t = t2[r];
            #pragma unroll
            for (int m = 1; m < 16; m <<= 1) {
                Top2 o;
                o.s1 = __shfl_xor(t.s1, m); o.i1 = __shfl_xor(t.i1, m);
                o.s2 = __shfl_xor(t.s2, m); o.i2 = __shfl_xor(t.i2, m);
                t = merge2(t, o);
            }
            if (lane16 == 0) {
                int row = m0 + wave * 16 + quad * 4 + r;
                part[(size_t)row * 8 + slot] =
                    make_float4(t.s1, __int_as_float(t.i1),
                                t.s2, __int_as_float(t.i2));
            }
            t2[r] = Top2{-3.4e38f, 0x7fffffff, -3.4e38f, 0x7fffffff};
        }
    };

    // prologue: cnorm(g0) FIRST (so PIPE_SYNC(2) completes it), then
    // sub-slices 0..2. Post-sync queue = {st1, st2}; af/cn/st0 complete.
    if (wave == 0)
        gll16(cnorm + (size_t)(nh * 32) * 128 + (lane & 31) * 4, lds + 32768);
    STAGE(0); STAGE(1); STAGE(2);
    PIPE_SYNC(2);

    for (int g = 0; g < 31; ++g) {
        floatx4 acc[8];
        ACCINIT(g, acc);
        const int u0 = g * 8;
        #pragma unroll
        for (int hh = 0; hh < 8; ++hh) {
            STAGE(u0 + hh + 3);
            if (hh == 3 && wave == 0)   // cnorm for g+1 rides the pipe;
                                        // complete by hh==5's sync < ACCINIT(g+1)
                gll16(cnorm + (size_t)(nh * 32 + g + 1) * 128 + (lane & 31) * 4,
                      lds + 32768 + ((g + 1) & 1) * 1024);
            COMPUTE(hh, acc);
            PIPE_SYNC(2);               // completes st(u0+hh+1)
        }
        TOP2(nh * 32 + g, acc);
        if ((g & 7) == 7) FLUSH((g >> 3) + nh * 4);
    }
    {   // g = 31 peeled: stages 251..255, then descending drains 1, 0
        floatx4 acc[8];
        ACCINIT(31, acc);
        #pragma unroll
        for (int hh = 0; hh < 5; ++hh) {
            STAGE(251 + hh);
            COMPUTE(hh, acc);
            PIPE_SYNC(2);
        }
        COMPUTE(5, acc); PIPE_SYNC(1);
        COMPUTE(6, acc); PIPE_SYNC(0);
        COMPUTE(7, acc);
        TOP2(nh * 32 + 31, acc);
        FLUSH(3 + nh * 4);
    }
}

// ---- 3. resolve: merge 8 partials/row + WAVE-COOPERATIVE fp64 refine ----
// Compact (row,cand) pairs to LDS, one wave per candidate (64 lanes x 4 dims,
// fp64 shuffle-reduce), then each row scans its results. zero_vq folded in.
__global__ __launch_bounds__(256) void resolve(const float4* __restrict__ part,
                                               const float* __restrict__ gr,
                                               const float* __restrict__ gi,
                                               const float* __restrict__ cb,
                                               int* __restrict__ idx,
                                               float* __restrict__ out,
                                               size_t vq_off) {
    __shared__ int s_cnt;
    __shared__ int2 ent[2048];
    __shared__ double res[2048];

    const int tid = threadIdx.x;
    const int row = blockIdx.x * 256 + tid;   // grid 128
    if (blockIdx.x == 0 && tid == 0) out[vq_off] = 0.f;
    if (tid == 0) s_cnt = 0;

    float4 e[8];
    #pragma unroll
    for (int j = 0; j < 8; ++j) e[j] = part[(size_t)row * 8 + j];
    Top2 t{-3.4e38f, 0x7fffffff, -3.4e38f, 0x7fffffff};
    #pragma unroll
    for (int j = 0; j < 8; ++j) {
        Top2 o{e[j].x, __float_as_int(e[j].y), e[j].z, __float_as_int(e[j].w)};
        t = merge2(t, o);
    }
    int best = t.i1;
    const float MARGIN = 0.12f;   // ~7.7 sigma of f16-screen score-diff noise
    const float cut = t.s1 - MARGIN;
    const bool need = (t.s1 - t.s2 < MARGIN);
    __syncthreads();              // s_cnt initialized

    int nc = 0;
    if (need) {
        #pragma unroll
        for (int j = 0; j < 8; ++j)
            #pragma unroll
            for (int c = 0; c < 2; ++c) {
                float sv = c ? e[j].z : e[j].x;
                int   ci = __float_as_int(c ? e[j].w : e[j].y);
                nc += (sv >= cut && (unsigned)ci < 8192u) ? 1 : 0;
            }
    }
    int mybase = 0;
    bool serial = false;
    if (nc) {
        mybase = atomicAdd(&s_cnt, nc);
        if (mybase + nc <= 2048) {
            int k = 0;
            #pragma unroll
            for (int j = 0; j < 8; ++j)
                #pragma unroll
                for (int c = 0; c < 2; ++c) {
                    float sv = c ? e[j].z : e[j].x;
                    int   ci = __float_as_int(c ? e[j].w : e[j].y);
                    if (sv >= cut && (unsigned)ci < 8192u)
                        ent[mybase + (k++)] = make_int2(row, ci);
                }
        } else serial = true;     // overflow fallback (needs >8 cands/row avg)
    }
    __syncthreads();
    const int cnt = (s_cnt < 2048) ? s_cnt : 2048;
    const int wave = tid >> 6, lane = tid & 63;
    for (int ee = wave; ee < cnt; ee += 4) {
        int2 rc = ent[ee];
        float4 c4 = ((const float4*)(cb + (size_t)rc.y * 256))[lane];
        float4 z4 = (lane < 32)
                  ? ((const float4*)(gr + (size_t)rc.x * 128))[lane]
                  : ((const float4*)(gi + (size_t)rc.x * 128))[lane - 32];
        double dx = (double)z4.x - (double)c4.x;
        double dy = (double)z4.y - (double)c4.y;
        double dz = (double)z4.z - (double)c4.z;
        double dw = (double)z4.w - (double)c4.w;
        double d = dx * dx + dy * dy + dz * dz + dw * dw;
        #pragma unroll
        for (int m = 1; m < 64; m <<= 1) d += __shfl_xor(d, m);
        if (lane == 0) res[ee] = d;
    }
    __syncthreads();
    if (nc && !serial) {
        double bd = 1e300; int bi = 0x7fffffff;
        for (int k = 0; k < nc; ++k) {
            double d = res[mybase + k];
            int   ci = ent[mybase + k].y;
            if (d < bd || (d == bd && ci < bi)) { bd = d; bi = ci; }
        }
        if ((unsigned)bi < 8192u) best = bi;
    } else if (serial) {          // old proven serial path (rare)
        double bd = 1e300; int bi = 0x7fffffff;
        const float* zr = gr + (size_t)row * 128;
        const float* zi = gi + (size_t)row * 128;
        #pragma unroll
        for (int j = 0; j < 8; ++j)
            #pragma unroll
            for (int c = 0; c < 2; ++c) {
                float sv = c ? e[j].z : e[j].x;
                int   ci = __float_as_int(c ? e[j].w : e[j].y);
                if (sv >= cut && (unsigned)ci < 8192u) {
                    const float* crow = cb + (size_t)ci * 256;
                    double d = 0.0;
                    for (int k = 0; k < 128; ++k) {
                        double a = (double)zr[k] - (double)crow[k];
                        double b = (double)zi[k] - (double)crow[128 + k];
                        d += a * a + b * b;
                    }
                    if (d < bd || (d == bd && ci < bi)) { bd = d; bi = ci; }
                }
            }
        if ((unsigned)bi < 8192u) best = bi;
    }
    idx[row] = ((unsigned)best < 8192u) ? best : 0;
}

// ---- 4. gather + proposal(REAL part only) + salience + vq (one wave/row) ----
__global__ __launch_bounds__(256) void gather_epi(const int* __restrict__ idx,
                                                  const float* __restrict__ gr,
                                                  const float* __restrict__ gi,
                                                  const float* __restrict__ cb,
                                                  const float* __restrict__ salw,
                                                  const float* __restrict__ salb,
                                                  float* __restrict__ out,
                                                  size_t sal_off, size_t vq_off) {
    const int wave = threadIdx.x >> 6, lane = threadIdx.x & 63;
    const int row = blockIdx.x * 4 + wave;
    int id = idx[row];
    if ((unsigned)id >= 8192u) id = 0;   // clamp: no wild reads

    float4 c4 = ((const float4*)(cb + (size_t)id * 256))[lane];
    float4 z4 = (lane < 32) ? ((const float4*)(gr + (size_t)row * 128))[lane]
                            : ((const float4*)(gi + (size_t)row * 128))[lane - 32];

    float dx = c4.x - z4.x, dy = c4.y - z4.y, dz = c4.z - z4.z, dw = c4.w - z4.w;
    float vq = dx * dx + dy * dy + dz * dz + dw * dw;
    float4 w4 = ((const float4*)salw)[lane];
    float sal = c4.x * w4.x + c4.y * w4.y + c4.z * w4.z + c4.w * w4.w;
    #pragma unroll
    for (int m = 1; m < 64; m <<= 1) {
        vq  += __shfl_xor(vq, m);
        sal += __shfl_xor(sal, m);
    }

    // proposal: real part only — lanes 0..31 hold c[0..128) as float4s
    if (lane < 32 && (size_t)(row + 1) * 128 <= sal_off) {
        float4* op = (float4*)(out + (size_t)row * 128);
        op[lane] = c4;
    }
    if (lane == 0 && sal_off + row < vq_off)
        out[sal_off + row] = sal + salb[0];

    __shared__ float vqs[4];
    if (lane == 0) vqs[wave] = vq;
    __syncthreads();
    if (threadIdx.x == 0) {
        float p = (vqs[0] + vqs[1] + vqs[2] + vqs[3]) * (1.25f / 8388608.f);
        atomicAdd(out + vq_off, p);
    }
}

extern "C" void kernel_launch(void* const* d_in, const int* in_sizes, int n_in,
                              void* d_out, int out_size, void* d_ws, size_t ws_size,
                              hipStream_t stream) {
    const float* gr = (const float*)d_in[0];   // gw_real  [8,4096,128]
    const float* gi = (const float*)d_in[1];   // gw_imag  [8,4096,128]
    const float* cb = (const float*)d_in[2];   // codebook [8192,256]
    const float* sw = (const float*)d_in[3];   // sal_w    [1,256]
    const float* sb = (const float*)d_in[4];   // sal_b    [1]
    float* out = (float*)d_out;

    // Output offsets (out_size = 4,227,073 floats:
    // proposal-real 4,194,304 | salience 32,768 | vq_loss 1).
    size_t vq_off  = (size_t)out_size - 1;
    size_t sal_off = (size_t)out_size - 1 - 32768;

    char* base = (char*)d_ws;
    int*  idxb = (int*)(base + IDX_OFF);
    _Float16* Bq   = (_Float16*)(base + B_OFF);
    float*    cn   = (float*)   (base + CN_OFF);
    float4*   part = (float4*)  (base + PART_OFF);

    prep_c<<<2048, 256, 0, stream>>>(cb, Bq, cn);
    gemm_argmin<<<512, 512, 0, stream>>>(gr, gi, Bq, cn, part);
    resolve<<<128, 256, 0, stream>>>(part, gr, gi, cb, idxb, out, vq_off);
    gather_epi<<<8192, 256, 0, stream>>>(idxb, gr, gi, cb, sw, sb, out,
                                         sal_off, vq_off);
}